// Round 20
// baseline (98.916 us; speedup 1.0000x reference)
//
#include <hip/hip_runtime.h>
#include <math.h>

#define TKK 512
#define TQQ 128
#define BB  8
#define EE  128
#define DD  82
#define IND 41
#define HH  128
#define G3  384
#define NL  50
#define OD  40

typedef __attribute__((ext_vector_type(8))) short short8v;
typedef __attribute__((ext_vector_type(4))) float f32x4;
#define MFMA16(a, b, c) __builtin_amdgcn_mfma_f32_16x16x32_bf16(a, b, c, 0, 0, 0)
#define RCP(x) __builtin_amdgcn_rcpf(x)

__device__ __forceinline__ short f2bf(float f) {
  unsigned u = __float_as_uint(f);
  unsigned r = (u + 0x7fffu + ((u >> 16) & 1u)) >> 16;  // RNE
  return (short)r;
}
__device__ __forceinline__ float dot4(float4 a, float4 b) {
  return a.x * b.x + a.y * b.y + a.z * b.z + a.w * b.w;
}

// ---------------- Kernel A: time embeddings + K/Q projections + gwi->bf16 ----------------
// blocks [0,512): kproj rows; [512,528): qproj rows; [528,624): convert gwi to bf16
// gwi_bf layout: [768][128] bf16, rows 0..383 = gwi_f, 384..767 = gwi_b.
__global__ __launch_bounds__(128) void embed_project(
    const float* __restrict__ time_steps, const float* __restrict__ query,
    const float* __restrict__ e1_wp, const float* __restrict__ e1_bp,
    const float* __restrict__ e1_wl, const float* __restrict__ e1_bl,
    const float* __restrict__ e2_wp, const float* __restrict__ e2_bp,
    const float* __restrict__ e2_wl, const float* __restrict__ e2_bl,
    const float* __restrict__ Wk, const float* __restrict__ bk,
    const float* __restrict__ Wq, const float* __restrict__ bq,
    const float* __restrict__ gwi_f, const float* __restrict__ gwi_b,
    float* __restrict__ kproj, float* __restrict__ qproj,
    unsigned short* __restrict__ gwi_bf) {
  __shared__ float emb[8][EE];
  int i = blockIdx.x;
  int e = threadIdx.x;
  if (i >= 528) {
    int base = (i - 528) * 1024 + e * 8;
#pragma unroll
    for (int r = 0; r < 8; r++) {
      int j = base + r;
      float v = (j < 49152) ? gwi_f[j] : gwi_b[j - 49152];
      gwi_bf[j] = (unsigned short)f2bf(v);
    }
    return;
  }
  const float *wp, *bp, *wl, *bl, *W, *bias;
  float* out;
  int row0;
  const float* tsrc;
  if (i < 512) {
    int b = i & 7, rg = i >> 3;
    row0 = b * TKK + rg * 8;
    tsrc = time_steps + row0;
    wp = e1_wp; bp = e1_bp; wl = e1_wl; bl = e1_bl; W = Wk; bias = bk;
    out = kproj + (size_t)row0 * EE;
  } else {
    int qg = i - 512;
    row0 = qg * 8;
    tsrc = query + row0;
    wp = e2_wp; bp = e2_bp; wl = e2_wl; bl = e2_bl; W = Wq; bias = bq;
    out = qproj + (size_t)row0 * EE;
  }
  float wpv = 0.f, bpv = 0.f;
  if (e > 0) { wpv = wp[e - 1]; bpv = bp[e - 1]; }
  float wlv = wl[0], blv = bl[0];
#pragma unroll
  for (int r = 0; r < 8; r++) {
    float t = tsrc[r];
    emb[r][e] = (e == 0) ? (t * wlv + blv) : sinf(t * wpv + bpv);
  }
  __syncthreads();
  const float4* wr4 = (const float4*)(W + (size_t)e * EE);
  const float4* em4 = (const float4*)emb;
  float bv = bias[e];
  float acc[8];
#pragma unroll
  for (int r = 0; r < 8; r++) acc[r] = bv;
#pragma unroll 4
  for (int c = 0; c < 32; c++) {
    float4 wv = wr4[c];
#pragma unroll
    for (int r = 0; r < 8; r++) acc[r] += dot4(wv, em4[r * 32 + c]);
  }
#pragma unroll
  for (int r = 0; r < 8; r++) out[(size_t)r * EE + e] = acc[r];
}

// ---------------- Kernel B: attention + Wo + gi(MFMA), 512 threads ----------------
// 256 blocks: b = bid&7 (XCD-local), qg = bid>>3, q = 4*qg..+4. 8 waves/block.
// Scores: 4-lane-per-row quads + shfl_xor. Wo staged in LDS.
// gi phase: xs(16x128 bf16, rows 4..15 zero) x gwiT via mfma_f32_16x16x32_bf16,
// B-fragments straight from gwi_bf (bf16, no unpack). 6 N-tiles/wave, 24 MFMAs.
// gi layout: float4 [(dir*8+b)*TQQ + t][col]{r,z,n,pad}
__global__ __launch_bounds__(512) void attention(
    const float* __restrict__ x, const float* __restrict__ kproj,
    const float* __restrict__ qproj, const float* __restrict__ Wo,
    const float* __restrict__ bo,
    const unsigned short* __restrict__ gwi_bf,
    const float* __restrict__ gbi_f, const float* __restrict__ gbi_b,
    float* __restrict__ gi) {
  __shared__ float qv[4][EE];
  __shared__ float4 w4[TKK];
  __shared__ float red[8][4];
  __shared__ float mfin[4];
  __shared__ float part[4][4][DD];
  __shared__ float numb[4][DD];
  __shared__ float attb[4][DD];
  __shared__ __align__(16) short xsr_bf[16][EE];  // bf16 xs, rows 4..15 zero
  __shared__ float wo_lds[HH * DD];  // 41 KB
  int b = blockIdx.x & 7, qg = blockIdx.x >> 3;
  int q0 = qg * 4;
  int tid = threadIdx.x;  // 0..511
  int rq = tid >> 2, ec = tid & 3;  // quad layout: 4 lanes per row

  // stage 4 qproj rows + Wo (linear coalesced copy) + zero xsr_bf
  {
    qv[tid >> 7][tid & 127] = qproj[(size_t)(q0 + (tid >> 7)) * EE + (tid & 127)];
    const float4* wo4 = (const float4*)Wo;
    float4* wl4 = (float4*)wo_lds;
#pragma unroll
    for (int it = 0; it < 6; it++) {
      int i4 = tid + it * 512;
      if (i4 < HH * DD / 4) wl4[i4] = wo4[i4];
    }
    ((int*)xsr_bf)[tid] = 0;
    ((int*)xsr_bf)[tid + 512] = 0;
  }
  __syncthreads();

  // ---- scores: 4 passes x 128 rows; quad covers one row ----
  const float scale = 0.08838834764831845f;  // 1/sqrt(128)
  float lm[4] = {-1e30f, -1e30f, -1e30f, -1e30f};
  const float4* qv4 = (const float4*)qv;
  for (int p = 0; p < 4; p++) {
    int r = p * 128 + rq;
    const float4* kr = (const float4*)(kproj + (size_t)(b * TKK + r) * EE);
    float s[4] = {0.f, 0.f, 0.f, 0.f};
#pragma unroll
    for (int c = 0; c < 8; c++) {
      float4 kv = kr[c * 4 + ec];
#pragma unroll
      for (int qi = 0; qi < 4; qi++) s[qi] += dot4(kv, qv4[qi * 32 + c * 4 + ec]);
    }
#pragma unroll
    for (int qi = 0; qi < 4; qi++) {
      s[qi] += __shfl_xor(s[qi], 1, 64);
      s[qi] += __shfl_xor(s[qi], 2, 64);
      s[qi] *= scale;
      lm[qi] = fmaxf(lm[qi], s[qi]);
    }
    if (ec == 0) { float4 sv = {s[0], s[1], s[2], s[3]}; w4[r] = sv; }
  }
  for (int off = 32; off; off >>= 1)
#pragma unroll
    for (int qi = 0; qi < 4; qi++) lm[qi] = fmaxf(lm[qi], __shfl_xor(lm[qi], off, 64));
  if ((tid & 63) == 0)
#pragma unroll
    for (int qi = 0; qi < 4; qi++) red[tid >> 6][qi] = lm[qi];
  __syncthreads();
  if (tid < 4) {
    float m = red[0][tid];
#pragma unroll
    for (int w = 1; w < 8; w++) m = fmaxf(m, red[w][tid]);
    mfin[tid] = m;
  }
  __syncthreads();
  {
    float m0 = mfin[0], m1 = mfin[1], m2 = mfin[2], m3 = mfin[3];
    float4 v0 = w4[tid];
    v0.x = __expf(v0.x - m0); v0.y = __expf(v0.y - m1);
    v0.z = __expf(v0.z - m2); v0.w = __expf(v0.w - m3);
    w4[tid] = v0;
  }
  __syncthreads();

  // ---- weighted numerators: chunk c2 (128 k) x feature d ----
  {
    int c2 = tid >> 7, d = tid & 127;
    if (d < DD) {
      const float* xp = x + ((size_t)(b * TKK + c2 * 128)) * DD + d;
      float a0 = 0.f, a1 = 0.f, a2 = 0.f, a3 = 0.f;
#pragma unroll 8
      for (int k = 0; k < 128; k++) {
        float xv = xp[(size_t)k * DD];
        float4 wv = w4[c2 * 128 + k];
        a0 += wv.x * xv; a1 += wv.y * xv; a2 += wv.z * xv; a3 += wv.w * xv;
      }
      part[c2][0][d] = a0; part[c2][1][d] = a1; part[c2][2][d] = a2; part[c2][3][d] = a3;
    }
  }
  __syncthreads();
  if (tid < DD) {
#pragma unroll
    for (int qi = 0; qi < 4; qi++)
      numb[qi][tid] = part[0][qi][tid] + part[1][qi][tid] + part[2][qi][tid] + part[3][qi][tid];
  }
  __syncthreads();
  if (tid < DD) {
    int j = tid % IND;
#pragma unroll
    for (int qi = 0; qi < 4; qi++)
      attb[qi][tid] = numb[qi][tid] * RCP(numb[qi][IND + j]);
  }
  __syncthreads();

  // ---- Wo projection from LDS: one (q,o) per thread -> xsr_bf ----
  {
    int o = tid & 127, g = tid >> 7;
    const float* wrow = wo_lds + o * DD;
    float acc = bo[o];
#pragma unroll 2
    for (int d = 0; d < DD; d++) acc += wrow[d] * attb[g][d];
    xsr_bf[g][o] = f2bf(acc);
  }
  __syncthreads();

  // ---- gi via MFMA: A = xs (M=16, q rows), B = gwi rows (N-tiles), K=128 ----
  {
    int wv = tid >> 6, ln = tid & 63;
    int lm16 = ln & 15, lk = ln >> 4;
    short8v Afr[4];
    const short* arow = &xsr_bf[lm16][0];
#pragma unroll
    for (int kk = 0; kk < 4; kk++)
      Afr[kk] = *(const short8v*)(arow + kk * 32 + lk * 8);
#pragma unroll
    for (int it = 0; it < 6; it++) {
      int ntile = wv * 6 + it;
      int n0 = ntile * 16;
      const unsigned short* brow = gwi_bf + (size_t)(n0 + lm16) * EE;
      f32x4 acc = {0.f, 0.f, 0.f, 0.f};
#pragma unroll
      for (int kk = 0; kk < 4; kk++) {
        short8v Bfr = *(const short8v*)(brow + kk * 32 + lk * 8);
        acc = MFMA16(Afr[kk], Bfr, acc);
      }
      if (lk == 0) {
        int ng = n0 + lm16;
        int dirn = (ng >= G3) ? 1 : 0;
        int oo = ng - dirn * G3;
        int gate = oo >> 7, col = oo & 127;
        float bi = (dirn ? gbi_b : gbi_f)[oo];
        float* gp = gi + (((size_t)(dirn * BB + b) * TQQ + q0) * HH + col) * 4 + gate;
#pragma unroll
        for (int j = 0; j < 4; j++) gp[j * 512] = acc[j] + bi;
      }
    }
  }
}

// ---------------- Kernel D: sequential GRU via MFMA (r12's 52.5 µs champion) ----------------
// 16 blocks = (dir, b), b = wgid&7 (XCD-local). 512 threads = 8 waves.
__global__ __launch_bounds__(512, 1) void gru_seq(const float* __restrict__ gi,
                                                  const float* __restrict__ gwh_f,
                                                  const float* __restrict__ gbh_f,
                                                  const float* __restrict__ gwh_b,
                                                  const float* __restrict__ gbh_b,
                                                  float* __restrict__ hcat) {
  __shared__ short hb[2][HH];  // 2 x 128 bf16
  int dir = blockIdx.x >> 3, b = blockIdx.x & 7;
  const float* Wh = dir ? gwh_b : gwh_f;
  const float* bh = dir ? gbh_b : gbh_f;
  int tid = threadIdx.x;
  int w = tid >> 6, l = tid & 63;
  int lhi = l >> 4, llo = l & 15;
  int o = 16 * w + llo;
  bool tl = (lhi == 0);

  for (int i = tid; i < 2 * HH / 2; i += 512) ((int*)hb)[i] = 0;

  short8v Bf[3][4];
#pragma unroll
  for (int g = 0; g < 3; g++) {
    const float* wr = Wh + (size_t)(g * HH + o) * EE;
#pragma unroll
    for (int kk = 0; kk < 4; kk++) {
      int k0 = kk * 32 + lhi * 8;
      short8v v;
#pragma unroll
      for (int i = 0; i < 8; i++) v[i] = f2bf(wr[k0 + i]);
      Bf[g][kk] = v;
    }
  }
  float bhr = bh[o], bhz = bh[HH + o], bhn = bh[2 * HH + o];
  float hprev = 0.f;
  float hst[16];  // store buffer, compile-time indices only

  float4 g0, g1, g2, g3;
  const size_t dbase = ((size_t)(dir * BB + b) * TQQ) * 512 + (size_t)o * 4;

  auto gi_load = [&](int step, float4& dst) {
    int tt = dir ? (TQQ - 1 - step) : step;
    dst = *(const float4*)(gi + dbase + (size_t)tt * 512);
  };
  __syncthreads();
  gi_load(0, g0); gi_load(1, g1);

  auto body = [&](int step, float4& gc, float4& gn, float& hs) {
    int cur = step & 1;
    const char* hrow = (const char*)&hb[cur][0];
    int ao = lhi * 16;
    short8v A0 = *(const short8v*)(hrow + 0 * 64 + ao);
    short8v A1 = *(const short8v*)(hrow + 1 * 64 + ao);
    short8v A2 = *(const short8v*)(hrow + 2 * 64 + ao);
    short8v A3 = *(const short8v*)(hrow + 3 * 64 + ao);
    { int ls = step + 2; gi_load(ls > TQQ - 1 ? TQQ - 1 : ls, gn); }
    f32x4 z4 = {0.f, 0.f, 0.f, 0.f};
    f32x4 aR = z4, aZ = z4, aN = z4;
    aR = MFMA16(A0, Bf[0][0], aR); aZ = MFMA16(A0, Bf[1][0], aZ); aN = MFMA16(A0, Bf[2][0], aN);
    aR = MFMA16(A1, Bf[0][1], aR); aZ = MFMA16(A1, Bf[1][1], aZ); aN = MFMA16(A1, Bf[2][1], aN);
    aR = MFMA16(A2, Bf[0][2], aR); aZ = MFMA16(A2, Bf[1][2], aZ); aN = MFMA16(A2, Bf[2][2], aN);
    aR = MFMA16(A3, Bf[0][3], aR); aZ = MFMA16(A3, Bf[1][3], aZ); aN = MFMA16(A3, Bf[2][3], aN);
    if (tl) {
      float rp = gc.x + bhr + aR[0];
      float zp = gc.y + bhz + aZ[0];
      float hn = aN[0] + bhn;
      float r = RCP(1.f + __expf(-rp));
      float z = RCP(1.f + __expf(-zp));
      float a = gc.z + r * hn;
      float e = __expf(2.f * a);
      float n = 1.f - 2.f * RCP(1.f + e);  // tanh(a), saturation-safe
      float hnew = n + z * (hprev - n);
      hprev = hnew;
      hs = hnew;
      hb[cur ^ 1][o] = f2bf(hnew);
    }
    asm volatile("s_waitcnt lgkmcnt(0)" ::: "memory");
    __builtin_amdgcn_s_barrier();
    __builtin_amdgcn_sched_barrier(0);
  };

  for (int so = 0; so < TQQ / 16; so++) {
    int s0i = so * 16;
    body(s0i + 0,  g0, g2, hst[0]);
    body(s0i + 1,  g1, g3, hst[1]);
    body(s0i + 2,  g2, g0, hst[2]);
    body(s0i + 3,  g3, g1, hst[3]);
    body(s0i + 4,  g0, g2, hst[4]);
    body(s0i + 5,  g1, g3, hst[5]);
    body(s0i + 6,  g2, g0, hst[6]);
    body(s0i + 7,  g3, g1, hst[7]);
    body(s0i + 8,  g0, g2, hst[8]);
    body(s0i + 9,  g1, g3, hst[9]);
    body(s0i + 10, g2, g0, hst[10]);
    body(s0i + 11, g3, g1, hst[11]);
    body(s0i + 12, g0, g2, hst[12]);
    body(s0i + 13, g1, g3, hst[13]);
    body(s0i + 14, g2, g0, hst[14]);
    body(s0i + 15, g3, g1, hst[15]);
    if (tl) {
#pragma unroll
      for (int si = 0; si < 16; si++) {
        int step = s0i + si;
        int t = dir ? (TQQ - 1 - step) : step;
        hcat[((size_t)b * TQQ + t) * (2 * HH) + dir * HH + o] = hst[si];
      }
    }
  }
}

// ---------------- Kernel E: final MLP, 8 rows/block ----------------
__global__ __launch_bounds__(512) void mlp_out(const float* __restrict__ hcat,
                                               const float* __restrict__ W1,
                                               const float* __restrict__ b1,
                                               const float* __restrict__ W2,
                                               const float* __restrict__ b2,
                                               float* __restrict__ out) {
  __shared__ float hrow[8][2 * HH];
  __shared__ float ybuf[8][52];
  int i = blockIdx.x;
  int b = i & 7, tg = i >> 3;
  int tid = threadIdx.x;
  size_t rowbase = (size_t)(b * TQQ + tg * 8) * (2 * HH);
  ((float4*)hrow)[tid] = *(const float4*)(hcat + rowbase + tid * 4);
  __syncthreads();
  int r = tid >> 6, o = tid & 63;
  if (o < NL) {
    const float4* w1 = (const float4*)(W1 + (size_t)o * (2 * HH));
    const float4* h4 = (const float4*)hrow[r];
    float acc = b1[o];
#pragma unroll 8
    for (int c = 0; c < 64; c++) acc += dot4(w1[c], h4[c]);
    ybuf[r][o] = fmaxf(acc, 0.f);
  }
  __syncthreads();
  if (o < OD) {
    const float* w2 = W2 + (size_t)o * NL;
    float acc = b2[o];
#pragma unroll 10
    for (int j = 0; j < NL; j++) acc += w2[j] * ybuf[r][j];
    out[((size_t)(b * TQQ + tg * 8) + r) * OD + o] = acc;
  }
}

extern "C" void kernel_launch(void* const* d_in, const int* in_sizes, int n_in,
                              void* d_out, int out_size, void* d_ws, size_t ws_size,
                              hipStream_t stream) {
  const float* x          = (const float*)d_in[0];
  const float* time_steps = (const float*)d_in[1];
  const float* query      = (const float*)d_in[2];
  const float* e1_wp = (const float*)d_in[3];
  const float* e1_bp = (const float*)d_in[4];
  const float* e1_wl = (const float*)d_in[5];
  const float* e1_bl = (const float*)d_in[6];
  const float* e2_wp = (const float*)d_in[7];
  const float* e2_bp = (const float*)d_in[8];
  const float* e2_wl = (const float*)d_in[9];
  const float* e2_bl = (const float*)d_in[10];
  const float* Wq = (const float*)d_in[11];
  const float* bq = (const float*)d_in[12];
  const float* Wk = (const float*)d_in[13];
  const float* bk = (const float*)d_in[14];
  const float* Wo = (const float*)d_in[15];
  const float* bo = (const float*)d_in[16];
  const float* gwi_f = (const float*)d_in[17];
  const float* gwh_f = (const float*)d_in[18];
  const float* gbi_f = (const float*)d_in[19];
  const float* gbh_f = (const float*)d_in[20];
  const float* gwi_b = (const float*)d_in[21];
  const float* gwh_b = (const float*)d_in[22];
  const float* gbi_b = (const float*)d_in[23];
  const float* gbh_b = (const float*)d_in[24];
  const float* W1 = (const float*)d_in[25];
  const float* b1 = (const float*)d_in[26];
  const float* W2 = (const float*)d_in[27];
  const float* b2 = (const float*)d_in[28];

  float* ws    = (float*)d_ws;
  float* kproj = ws;                        // 4096*128
  float* qproj = kproj + 4096 * 128;        // 128*128
  float* gi    = qproj + 128 * 128;         // float4 [16*128][128]
  float* hcat  = gi + 16 * 128 * 128 * 4;   // 8*128*256
  unsigned short* gwi_bf = (unsigned short*)(hcat + 8 * 128 * 256);  // [768][128]

  embed_project<<<624, 128, 0, stream>>>(time_steps, query,
                                         e1_wp, e1_bp, e1_wl, e1_bl,
                                         e2_wp, e2_bp, e2_wl, e2_bl,
                                         Wk, bk, Wq, bq, gwi_f, gwi_b,
                                         kproj, qproj, gwi_bf);
  attention<<<256, 512, 0, stream>>>(x, kproj, qproj, Wo, bo,
                                     gwi_bf, gbi_f, gbi_b, gi);
  gru_seq<<<16, 512, 0, stream>>>(gi, gwh_f, gbh_f, gwh_b, gbh_b, hcat);
  mlp_out<<<128, 512, 0, stream>>>(hcat, W1, b1, W2, b2, (float*)d_out);
}

// Round 21
// 98.269 us; speedup vs baseline: 1.0066x; 1.0066x over previous
//
#include <hip/hip_runtime.h>
#include <math.h>

#define TKK 512
#define TQQ 128
#define BB  8
#define EE  128
#define DD  82
#define IND 41
#define HH  128
#define G3  384
#define NL  50
#define OD  40

typedef __attribute__((ext_vector_type(8))) short short8v;
typedef __attribute__((ext_vector_type(4))) float f32x4;
#define MFMA16(a, b, c) __builtin_amdgcn_mfma_f32_16x16x32_bf16(a, b, c, 0, 0, 0)
#define RCP(x) __builtin_amdgcn_rcpf(x)

__device__ __forceinline__ short f2bf(float f) {
  unsigned u = __float_as_uint(f);
  unsigned r = (u + 0x7fffu + ((u >> 16) & 1u)) >> 16;  // RNE
  return (short)r;
}
__device__ __forceinline__ float dot4(float4 a, float4 b) {
  return a.x * b.x + a.y * b.y + a.z * b.z + a.w * b.w;
}

// ---------------- Kernel A: time embeddings + K/Q projections ----------------
__global__ __launch_bounds__(128) void embed_project(
    const float* __restrict__ time_steps, const float* __restrict__ query,
    const float* __restrict__ e1_wp, const float* __restrict__ e1_bp,
    const float* __restrict__ e1_wl, const float* __restrict__ e1_bl,
    const float* __restrict__ e2_wp, const float* __restrict__ e2_bp,
    const float* __restrict__ e2_wl, const float* __restrict__ e2_bl,
    const float* __restrict__ Wk, const float* __restrict__ bk,
    const float* __restrict__ Wq, const float* __restrict__ bq,
    float* __restrict__ kproj, float* __restrict__ qproj) {
  __shared__ float emb[8][EE];
  int i = blockIdx.x;
  int e = threadIdx.x;
  const float *wp, *bp, *wl, *bl, *W, *bias;
  float* out;
  int row0;
  const float* tsrc;
  if (i < 512) {
    int b = i & 7, rg = i >> 3;
    row0 = b * TKK + rg * 8;
    tsrc = time_steps + row0;
    wp = e1_wp; bp = e1_bp; wl = e1_wl; bl = e1_bl; W = Wk; bias = bk;
    out = kproj + (size_t)row0 * EE;
  } else {
    int qg = i - 512;
    row0 = qg * 8;
    tsrc = query + row0;
    wp = e2_wp; bp = e2_bp; wl = e2_wl; bl = e2_bl; W = Wq; bias = bq;
    out = qproj + (size_t)row0 * EE;
  }
  float wpv = 0.f, bpv = 0.f;
  if (e > 0) { wpv = wp[e - 1]; bpv = bp[e - 1]; }
  float wlv = wl[0], blv = bl[0];
#pragma unroll
  for (int r = 0; r < 8; r++) {
    float t = tsrc[r];
    emb[r][e] = (e == 0) ? (t * wlv + blv) : sinf(t * wpv + bpv);
  }
  __syncthreads();
  const float4* wr4 = (const float4*)(W + (size_t)e * EE);
  const float4* em4 = (const float4*)emb;
  float bv = bias[e];
  float acc[8];
#pragma unroll
  for (int r = 0; r < 8; r++) acc[r] = bv;
#pragma unroll 4
  for (int c = 0; c < 32; c++) {
    float4 wv = wr4[c];
#pragma unroll
    for (int r = 0; r < 8; r++) acc[r] += dot4(wv, em4[r * 32 + c]);
  }
#pragma unroll
  for (int r = 0; r < 8; r++) out[(size_t)r * EE + e] = acc[r];
}

// ---------------- Kernel B: attention + Wo + gi (fused), 512 threads ----------------
// 256 blocks: b = bid&7 (XCD-local), qg = bid>>3, q = 4*qg..+4. 8 waves/block.
// Scores/gi: 4-lane-per-row quads + shfl_xor reduce. Wo staged in LDS.
// gi layout: float4 [(dir*8+b)*TQQ + t][col]{r,z,n,pad}
__global__ __launch_bounds__(512) void attention(
    const float* __restrict__ x, const float* __restrict__ kproj,
    const float* __restrict__ qproj, const float* __restrict__ Wo,
    const float* __restrict__ bo,
    const float* __restrict__ gwi_f, const float* __restrict__ gbi_f,
    const float* __restrict__ gwi_b, const float* __restrict__ gbi_b,
    float* __restrict__ gi) {
  __shared__ float qv[4][EE];
  __shared__ float4 w4[TKK];
  __shared__ float red[8][4];
  __shared__ float mfin[4];
  __shared__ float part[4][4][DD];
  __shared__ float numb[4][DD];
  __shared__ float attb[4][DD];
  __shared__ float xsr[4][EE];
  __shared__ float wo_lds[HH * DD];  // 41 KB
  int b = blockIdx.x & 7, qg = blockIdx.x >> 3;
  int q0 = qg * 4;
  int tid = threadIdx.x;  // 0..511
  int rq = tid >> 2, ec = tid & 3;  // quad layout: 4 lanes per row

  // stage 4 qproj rows + Wo (linear coalesced copy)
  {
    qv[tid >> 7][tid & 127] = qproj[(size_t)(q0 + (tid >> 7)) * EE + (tid & 127)];
    const float4* wo4 = (const float4*)Wo;
    float4* wl4 = (float4*)wo_lds;
#pragma unroll
    for (int it = 0; it < 6; it++) {
      int i4 = tid + it * 512;
      if (i4 < HH * DD / 4) wl4[i4] = wo4[i4];
    }
  }
  __syncthreads();

  // ---- scores: 4 passes x 128 rows; quad covers one row ----
  const float scale = 0.08838834764831845f;  // 1/sqrt(128)
  float lm[4] = {-1e30f, -1e30f, -1e30f, -1e30f};
  const float4* qv4 = (const float4*)qv;
  for (int p = 0; p < 4; p++) {
    int r = p * 128 + rq;
    const float4* kr = (const float4*)(kproj + (size_t)(b * TKK + r) * EE);
    float s[4] = {0.f, 0.f, 0.f, 0.f};
#pragma unroll
    for (int c = 0; c < 8; c++) {
      float4 kv = kr[c * 4 + ec];
#pragma unroll
      for (int qi = 0; qi < 4; qi++) s[qi] += dot4(kv, qv4[qi * 32 + c * 4 + ec]);
    }
#pragma unroll
    for (int qi = 0; qi < 4; qi++) {
      s[qi] += __shfl_xor(s[qi], 1, 64);
      s[qi] += __shfl_xor(s[qi], 2, 64);
      s[qi] *= scale;
      lm[qi] = fmaxf(lm[qi], s[qi]);
    }
    if (ec == 0) { float4 sv = {s[0], s[1], s[2], s[3]}; w4[r] = sv; }
  }
  for (int off = 32; off; off >>= 1)
#pragma unroll
    for (int qi = 0; qi < 4; qi++) lm[qi] = fmaxf(lm[qi], __shfl_xor(lm[qi], off, 64));
  if ((tid & 63) == 0)
#pragma unroll
    for (int qi = 0; qi < 4; qi++) red[tid >> 6][qi] = lm[qi];
  __syncthreads();
  if (tid < 4) {
    float m = red[0][tid];
#pragma unroll
    for (int w = 1; w < 8; w++) m = fmaxf(m, red[w][tid]);
    mfin[tid] = m;
  }
  __syncthreads();
  {
    float m0 = mfin[0], m1 = mfin[1], m2 = mfin[2], m3 = mfin[3];
    float4 v0 = w4[tid];
    v0.x = __expf(v0.x - m0); v0.y = __expf(v0.y - m1);
    v0.z = __expf(v0.z - m2); v0.w = __expf(v0.w - m3);
    w4[tid] = v0;
  }
  __syncthreads();

  // ---- weighted numerators: chunk c2 (128 k) x feature d ----
  {
    int c2 = tid >> 7, d = tid & 127;
    if (d < DD) {
      const float* xp = x + ((size_t)(b * TKK + c2 * 128)) * DD + d;
      float a0 = 0.f, a1 = 0.f, a2 = 0.f, a3 = 0.f;
#pragma unroll 8
      for (int k = 0; k < 128; k++) {
        float xv = xp[(size_t)k * DD];
        float4 wv = w4[c2 * 128 + k];
        a0 += wv.x * xv; a1 += wv.y * xv; a2 += wv.z * xv; a3 += wv.w * xv;
      }
      part[c2][0][d] = a0; part[c2][1][d] = a1; part[c2][2][d] = a2; part[c2][3][d] = a3;
    }
  }
  __syncthreads();
  if (tid < DD) {
#pragma unroll
    for (int qi = 0; qi < 4; qi++)
      numb[qi][tid] = part[0][qi][tid] + part[1][qi][tid] + part[2][qi][tid] + part[3][qi][tid];
  }
  __syncthreads();
  if (tid < DD) {
    int j = tid % IND;
#pragma unroll
    for (int qi = 0; qi < 4; qi++)
      attb[qi][tid] = numb[qi][tid] * RCP(numb[qi][IND + j]);
  }
  __syncthreads();

  // ---- Wo projection from LDS: one (q,o) per thread ----
  {
    int o = tid & 127, g = tid >> 7;
    const float* wrow = wo_lds + o * DD;
    float acc = bo[o];
#pragma unroll 2
    for (int d = 0; d < DD; d++) acc += wrow[d] * attb[g][d];
    xsr[g][o] = acc;
  }
  __syncthreads();

  // ---- gi: 6 passes x 128 weight rows; quad covers one row ----
  const float4* xs4 = (const float4*)xsr;
  for (int p = 0; p < 6; p++) {
    int o = p * 128 + rq;
    int dirn = (o >= G3) ? 1 : 0;
    int oo = o - dirn * G3;
    int gate = oo >> 7, col = oo & 127;
    const float4* wr = (const float4*)((dirn ? gwi_b : gwi_f) + (size_t)oo * EE);
    float a[4] = {0.f, 0.f, 0.f, 0.f};
#pragma unroll
    for (int c = 0; c < 8; c++) {
      float4 wv = wr[c * 4 + ec];
#pragma unroll
      for (int qi = 0; qi < 4; qi++) a[qi] += dot4(wv, xs4[qi * 32 + c * 4 + ec]);
    }
#pragma unroll
    for (int qi = 0; qi < 4; qi++) {
      a[qi] += __shfl_xor(a[qi], 1, 64);
      a[qi] += __shfl_xor(a[qi], 2, 64);
    }
    float bi = (dirn ? gbi_b : gbi_f)[oo];
    if (ec == 0) {
      float* gp = gi + (((size_t)(dirn * BB + b) * TQQ + q0) * HH + col) * 4 + gate;
      gp[0] = a[0] + bi; gp[512] = a[1] + bi; gp[1024] = a[2] + bi; gp[1536] = a[3] + bi;
    }
  }
}

// ---------------- Kernel D: sequential GRU via MFMA (r12's 52.5 µs champion) ----------------
// 16 blocks = (dir, b), b = wgid&7 (XCD-local). 512 threads = 8 waves.
__global__ __launch_bounds__(512, 1) void gru_seq(const float* __restrict__ gi,
                                                  const float* __restrict__ gwh_f,
                                                  const float* __restrict__ gbh_f,
                                                  const float* __restrict__ gwh_b,
                                                  const float* __restrict__ gbh_b,
                                                  float* __restrict__ hcat) {
  __shared__ short hb[2][HH];  // 2 x 128 bf16
  int dir = blockIdx.x >> 3, b = blockIdx.x & 7;
  const float* Wh = dir ? gwh_b : gwh_f;
  const float* bh = dir ? gbh_b : gbh_f;
  int tid = threadIdx.x;
  int w = tid >> 6, l = tid & 63;
  int lhi = l >> 4, llo = l & 15;
  int o = 16 * w + llo;
  bool tl = (lhi == 0);

  for (int i = tid; i < 2 * HH / 2; i += 512) ((int*)hb)[i] = 0;

  short8v Bf[3][4];
#pragma unroll
  for (int g = 0; g < 3; g++) {
    const float* wr = Wh + (size_t)(g * HH + o) * EE;
#pragma unroll
    for (int kk = 0; kk < 4; kk++) {
      int k0 = kk * 32 + lhi * 8;
      short8v v;
#pragma unroll
      for (int i = 0; i < 8; i++) v[i] = f2bf(wr[k0 + i]);
      Bf[g][kk] = v;
    }
  }
  float bhr = bh[o], bhz = bh[HH + o], bhn = bh[2 * HH + o];
  float hprev = 0.f;
  float hst[16];  // store buffer, compile-time indices only

  float4 g0, g1, g2, g3;
  const size_t dbase = ((size_t)(dir * BB + b) * TQQ) * 512 + (size_t)o * 4;

  auto gi_load = [&](int step, float4& dst) {
    int tt = dir ? (TQQ - 1 - step) : step;
    dst = *(const float4*)(gi + dbase + (size_t)tt * 512);
  };
  __syncthreads();
  gi_load(0, g0); gi_load(1, g1);

  auto body = [&](int step, float4& gc, float4& gn, float& hs) {
    int cur = step & 1;
    const char* hrow = (const char*)&hb[cur][0];
    int ao = lhi * 16;
    short8v A0 = *(const short8v*)(hrow + 0 * 64 + ao);
    short8v A1 = *(const short8v*)(hrow + 1 * 64 + ao);
    short8v A2 = *(const short8v*)(hrow + 2 * 64 + ao);
    short8v A3 = *(const short8v*)(hrow + 3 * 64 + ao);
    { int ls = step + 2; gi_load(ls > TQQ - 1 ? TQQ - 1 : ls, gn); }
    f32x4 z4 = {0.f, 0.f, 0.f, 0.f};
    f32x4 aR = z4, aZ = z4, aN = z4;
    aR = MFMA16(A0, Bf[0][0], aR); aZ = MFMA16(A0, Bf[1][0], aZ); aN = MFMA16(A0, Bf[2][0], aN);
    aR = MFMA16(A1, Bf[0][1], aR); aZ = MFMA16(A1, Bf[1][1], aZ); aN = MFMA16(A1, Bf[2][1], aN);
    aR = MFMA16(A2, Bf[0][2], aR); aZ = MFMA16(A2, Bf[1][2], aZ); aN = MFMA16(A2, Bf[2][2], aN);
    aR = MFMA16(A3, Bf[0][3], aR); aZ = MFMA16(A3, Bf[1][3], aZ); aN = MFMA16(A3, Bf[2][3], aN);
    if (tl) {
      float rp = gc.x + bhr + aR[0];
      float zp = gc.y + bhz + aZ[0];
      float hn = aN[0] + bhn;
      float r = RCP(1.f + __expf(-rp));
      float z = RCP(1.f + __expf(-zp));
      float a = gc.z + r * hn;
      float e = __expf(2.f * a);
      float n = 1.f - 2.f * RCP(1.f + e);  // tanh(a), saturation-safe
      float hnew = n + z * (hprev - n);
      hprev = hnew;
      hs = hnew;
      hb[cur ^ 1][o] = f2bf(hnew);
    }
    asm volatile("s_waitcnt lgkmcnt(0)" ::: "memory");
    __builtin_amdgcn_s_barrier();
    __builtin_amdgcn_sched_barrier(0);
  };

  for (int so = 0; so < TQQ / 16; so++) {
    int s0i = so * 16;
    body(s0i + 0,  g0, g2, hst[0]);
    body(s0i + 1,  g1, g3, hst[1]);
    body(s0i + 2,  g2, g0, hst[2]);
    body(s0i + 3,  g3, g1, hst[3]);
    body(s0i + 4,  g0, g2, hst[4]);
    body(s0i + 5,  g1, g3, hst[5]);
    body(s0i + 6,  g2, g0, hst[6]);
    body(s0i + 7,  g3, g1, hst[7]);
    body(s0i + 8,  g0, g2, hst[8]);
    body(s0i + 9,  g1, g3, hst[9]);
    body(s0i + 10, g2, g0, hst[10]);
    body(s0i + 11, g3, g1, hst[11]);
    body(s0i + 12, g0, g2, hst[12]);
    body(s0i + 13, g1, g3, hst[13]);
    body(s0i + 14, g2, g0, hst[14]);
    body(s0i + 15, g3, g1, hst[15]);
    if (tl) {
#pragma unroll
      for (int si = 0; si < 16; si++) {
        int step = s0i + si;
        int t = dir ? (TQQ - 1 - step) : step;
        hcat[((size_t)b * TQQ + t) * (2 * HH) + dir * HH + o] = hst[si];
      }
    }
  }
}

// ---------------- Kernel E: final MLP, 8 rows/block ----------------
__global__ __launch_bounds__(512) void mlp_out(const float* __restrict__ hcat,
                                               const float* __restrict__ W1,
                                               const float* __restrict__ b1,
                                               const float* __restrict__ W2,
                                               const float* __restrict__ b2,
                                               float* __restrict__ out) {
  __shared__ float hrow[8][2 * HH];
  __shared__ float ybuf[8][52];
  int i = blockIdx.x;
  int b = i & 7, tg = i >> 3;
  int tid = threadIdx.x;
  size_t rowbase = (size_t)(b * TQQ + tg * 8) * (2 * HH);
  ((float4*)hrow)[tid] = *(const float4*)(hcat + rowbase + tid * 4);
  __syncthreads();
  int r = tid >> 6, o = tid & 63;
  if (o < NL) {
    const float4* w1 = (const float4*)(W1 + (size_t)o * (2 * HH));
    const float4* h4 = (const float4*)hrow[r];
    float acc = b1[o];
#pragma unroll 8
    for (int c = 0; c < 64; c++) acc += dot4(w1[c], h4[c]);
    ybuf[r][o] = fmaxf(acc, 0.f);
  }
  __syncthreads();
  if (o < OD) {
    const float* w2 = W2 + (size_t)o * NL;
    float acc = b2[o];
#pragma unroll 10
    for (int j = 0; j < NL; j++) acc += w2[j] * ybuf[r][j];
    out[((size_t)(b * TQQ + tg * 8) + r) * OD + o] = acc;
  }
}

extern "C" void kernel_launch(void* const* d_in, const int* in_sizes, int n_in,
                              void* d_out, int out_size, void* d_ws, size_t ws_size,
                              hipStream_t stream) {
  const float* x          = (const float*)d_in[0];
  const float* time_steps = (const float*)d_in[1];
  const float* query      = (const float*)d_in[2];
  const float* e1_wp = (const float*)d_in[3];
  const float* e1_bp = (const float*)d_in[4];
  const float* e1_wl = (const float*)d_in[5];
  const float* e1_bl = (const float*)d_in[6];
  const float* e2_wp = (const float*)d_in[7];
  const float* e2_bp = (const float*)d_in[8];
  const float* e2_wl = (const float*)d_in[9];
  const float* e2_bl = (const float*)d_in[10];
  const float* Wq = (const float*)d_in[11];
  const float* bq = (const float*)d_in[12];
  const float* Wk = (const float*)d_in[13];
  const float* bk = (const float*)d_in[14];
  const float* Wo = (const float*)d_in[15];
  const float* bo = (const float*)d_in[16];
  const float* gwi_f = (const float*)d_in[17];
  const float* gwh_f = (const float*)d_in[18];
  const float* gbi_f = (const float*)d_in[19];
  const float* gbh_f = (const float*)d_in[20];
  const float* gwi_b = (const float*)d_in[21];
  const float* gwh_b = (const float*)d_in[22];
  const float* gbi_b = (const float*)d_in[23];
  const float* gbh_b = (const float*)d_in[24];
  const float* W1 = (const float*)d_in[25];
  const float* b1 = (const float*)d_in[26];
  const float* W2 = (const float*)d_in[27];
  const float* b2 = (const float*)d_in[28];

  float* ws    = (float*)d_ws;
  float* kproj = ws;                        // 4096*128
  float* qproj = kproj + 4096 * 128;        // 128*128
  float* gi    = qproj + 128 * 128;         // float4 [16*128][128]
  float* hcat  = gi + 16 * 128 * 128 * 4;   // 8*128*256

  embed_project<<<528, 128, 0, stream>>>(time_steps, query,
                                         e1_wp, e1_bp, e1_wl, e1_bl,
                                         e2_wp, e2_bp, e2_wl, e2_bl,
                                         Wk, bk, Wq, bq, kproj, qproj);
  attention<<<256, 512, 0, stream>>>(x, kproj, qproj, Wo, bo,
                                     gwi_f, gbi_f, gwi_b, gbi_b, gi);
  gru_seq<<<16, 512, 0, stream>>>(gi, gwh_f, gbh_f, gwh_b, gbh_b, hcat);
  mlp_out<<<128, 512, 0, stream>>>(hcat, W1, b1, W2, b2, (float*)d_out);
}

// Round 22
// 97.331 us; speedup vs baseline: 1.0163x; 1.0096x over previous
//
#include <hip/hip_runtime.h>
#include <math.h>

#define TKK 512
#define TQQ 128
#define BB  8
#define EE  128
#define DD  82
#define IND 41
#define HH  128
#define G3  384
#define NL  50
#define OD  40

typedef __attribute__((ext_vector_type(8))) short short8v;
typedef __attribute__((ext_vector_type(4))) float f32x4;
#define MFMA16(a, b, c) __builtin_amdgcn_mfma_f32_16x16x32_bf16(a, b, c, 0, 0, 0)
#define RCP(x) __builtin_amdgcn_rcpf(x)

__device__ __forceinline__ short f2bf(float f) {
  unsigned u = __float_as_uint(f);
  unsigned r = (u + 0x7fffu + ((u >> 16) & 1u)) >> 16;  // RNE
  return (short)r;
}
__device__ __forceinline__ float dot4(float4 a, float4 b) {
  return a.x * b.x + a.y * b.y + a.z * b.z + a.w * b.w;
}

// ---------------- Kernel A: time embeddings + K/Q projections ----------------
__global__ __launch_bounds__(128) void embed_project(
    const float* __restrict__ time_steps, const float* __restrict__ query,
    const float* __restrict__ e1_wp, const float* __restrict__ e1_bp,
    const float* __restrict__ e1_wl, const float* __restrict__ e1_bl,
    const float* __restrict__ e2_wp, const float* __restrict__ e2_bp,
    const float* __restrict__ e2_wl, const float* __restrict__ e2_bl,
    const float* __restrict__ Wk, const float* __restrict__ bk,
    const float* __restrict__ Wq, const float* __restrict__ bq,
    float* __restrict__ kproj, float* __restrict__ qproj) {
  __shared__ float emb[8][EE];
  int i = blockIdx.x;
  int e = threadIdx.x;
  const float *wp, *bp, *wl, *bl, *W, *bias;
  float* out;
  int row0;
  const float* tsrc;
  if (i < 512) {
    int b = i & 7, rg = i >> 3;
    row0 = b * TKK + rg * 8;
    tsrc = time_steps + row0;
    wp = e1_wp; bp = e1_bp; wl = e1_wl; bl = e1_bl; W = Wk; bias = bk;
    out = kproj + (size_t)row0 * EE;
  } else {
    int qg = i - 512;
    row0 = qg * 8;
    tsrc = query + row0;
    wp = e2_wp; bp = e2_bp; wl = e2_wl; bl = e2_bl; W = Wq; bias = bq;
    out = qproj + (size_t)row0 * EE;
  }
  float wpv = 0.f, bpv = 0.f;
  if (e > 0) { wpv = wp[e - 1]; bpv = bp[e - 1]; }
  float wlv = wl[0], blv = bl[0];
#pragma unroll
  for (int r = 0; r < 8; r++) {
    float t = tsrc[r];
    emb[r][e] = (e == 0) ? (t * wlv + blv) : sinf(t * wpv + bpv);
  }
  __syncthreads();
  const float4* wr4 = (const float4*)(W + (size_t)e * EE);
  const float4* em4 = (const float4*)emb;
  float bv = bias[e];
  float acc[8];
#pragma unroll
  for (int r = 0; r < 8; r++) acc[r] = bv;
#pragma unroll 4
  for (int c = 0; c < 32; c++) {
    float4 wv = wr4[c];
#pragma unroll
    for (int r = 0; r < 8; r++) acc[r] += dot4(wv, em4[r * 32 + c]);
  }
#pragma unroll
  for (int r = 0; r < 8; r++) out[(size_t)r * EE + e] = acc[r];
}

// ---------------- Kernel B: attention + Wo + gi (fused), 512 threads ----------------
// 256 blocks: b = bid&7 (XCD-local), qg = bid>>3, q = 4*qg..+4. 8 waves/block.
// No max-subtraction (softmax used only as num/den ratio; scores ~N(0,1) after
// 1/sqrt(128) scale, exp safe). 5 barrier phases: stage, scores+exp, PV,
// attb (num+den summed redundantly), Wo, gi.
// gi layout: float4 [(dir*8+b)*TQQ + t][col]{r,z,n,pad}
__global__ __launch_bounds__(512) void attention(
    const float* __restrict__ x, const float* __restrict__ kproj,
    const float* __restrict__ qproj, const float* __restrict__ Wo,
    const float* __restrict__ bo,
    const float* __restrict__ gwi_f, const float* __restrict__ gbi_f,
    const float* __restrict__ gwi_b, const float* __restrict__ gbi_b,
    float* __restrict__ gi) {
  __shared__ float qv[4][EE];
  __shared__ float4 w4[TKK];
  __shared__ float part[4][4][DD];
  __shared__ float attb[4][DD];
  __shared__ float xsr[4][EE];
  __shared__ float wo_lds[HH * DD];  // 41 KB
  int b = blockIdx.x & 7, qg = blockIdx.x >> 3;
  int q0 = qg * 4;
  int tid = threadIdx.x;  // 0..511
  int rq = tid >> 2, ec = tid & 3;  // quad layout: 4 lanes per row

  // stage 4 qproj rows + Wo (linear coalesced copy)
  {
    qv[tid >> 7][tid & 127] = qproj[(size_t)(q0 + (tid >> 7)) * EE + (tid & 127)];
    const float4* wo4 = (const float4*)Wo;
    float4* wl4 = (float4*)wo_lds;
#pragma unroll
    for (int it = 0; it < 6; it++) {
      int i4 = tid + it * 512;
      if (i4 < HH * DD / 4) wl4[i4] = wo4[i4];
    }
  }
  __syncthreads();

  // ---- scores + exp fused: 4 passes x 128 rows; quad covers one row ----
  const float scale = 0.08838834764831845f;  // 1/sqrt(128)
  const float4* qv4 = (const float4*)qv;
  for (int p = 0; p < 4; p++) {
    int r = p * 128 + rq;
    const float4* kr = (const float4*)(kproj + (size_t)(b * TKK + r) * EE);
    float s[4] = {0.f, 0.f, 0.f, 0.f};
#pragma unroll
    for (int c = 0; c < 8; c++) {
      float4 kv = kr[c * 4 + ec];
#pragma unroll
      for (int qi = 0; qi < 4; qi++) s[qi] += dot4(kv, qv4[qi * 32 + c * 4 + ec]);
    }
#pragma unroll
    for (int qi = 0; qi < 4; qi++) {
      s[qi] += __shfl_xor(s[qi], 1, 64);
      s[qi] += __shfl_xor(s[qi], 2, 64);
      s[qi] = __expf(s[qi] * scale);  // no max-subtraction: ratio-invariant
    }
    if (ec == 0) { float4 sv = {s[0], s[1], s[2], s[3]}; w4[r] = sv; }
  }
  __syncthreads();

  // ---- weighted numerators: chunk c2 (128 k) x feature d ----
  {
    int c2 = tid >> 7, d = tid & 127;
    if (d < DD) {
      const float* xp = x + ((size_t)(b * TKK + c2 * 128)) * DD + d;
      float a0 = 0.f, a1 = 0.f, a2 = 0.f, a3 = 0.f;
#pragma unroll 8
      for (int k = 0; k < 128; k++) {
        float xv = xp[(size_t)k * DD];
        float4 wv = w4[c2 * 128 + k];
        a0 += wv.x * xv; a1 += wv.y * xv; a2 += wv.z * xv; a3 += wv.w * xv;
      }
      part[c2][0][d] = a0; part[c2][1][d] = a1; part[c2][2][d] = a2; part[c2][3][d] = a3;
    }
  }
  __syncthreads();

  // ---- attb: num and den both summed here (no numb phase/barrier) ----
  if (tid < DD) {
    int j = IND + (tid % IND);
#pragma unroll
    for (int qi = 0; qi < 4; qi++) {
      float num = part[0][qi][tid] + part[1][qi][tid] + part[2][qi][tid] + part[3][qi][tid];
      float den = part[0][qi][j] + part[1][qi][j] + part[2][qi][j] + part[3][qi][j];
      attb[qi][tid] = num * RCP(den);
    }
  }
  __syncthreads();

  // ---- Wo projection from LDS: one (q,o) per thread ----
  {
    int o = tid & 127, g = tid >> 7;
    const float* wrow = wo_lds + o * DD;
    float acc = bo[o];
#pragma unroll 2
    for (int d = 0; d < DD; d++) acc += wrow[d] * attb[g][d];
    xsr[g][o] = acc;
  }
  __syncthreads();

  // ---- gi: 6 passes x 128 weight rows; quad covers one row ----
  const float4* xs4 = (const float4*)xsr;
  for (int p = 0; p < 6; p++) {
    int o = p * 128 + rq;
    int dirn = (o >= G3) ? 1 : 0;
    int oo = o - dirn * G3;
    int gate = oo >> 7, col = oo & 127;
    const float4* wr = (const float4*)((dirn ? gwi_b : gwi_f) + (size_t)oo * EE);
    float a[4] = {0.f, 0.f, 0.f, 0.f};
#pragma unroll
    for (int c = 0; c < 8; c++) {
      float4 wv = wr[c * 4 + ec];
#pragma unroll
      for (int qi = 0; qi < 4; qi++) a[qi] += dot4(wv, xs4[qi * 32 + c * 4 + ec]);
    }
#pragma unroll
    for (int qi = 0; qi < 4; qi++) {
      a[qi] += __shfl_xor(a[qi], 1, 64);
      a[qi] += __shfl_xor(a[qi], 2, 64);
    }
    float bi = (dirn ? gbi_b : gbi_f)[oo];
    if (ec == 0) {
      float* gp = gi + (((size_t)(dirn * BB + b) * TQQ + q0) * HH + col) * 4 + gate;
      gp[0] = a[0] + bi; gp[512] = a[1] + bi; gp[1024] = a[2] + bi; gp[1536] = a[3] + bi;
    }
  }
}

// ---------------- Kernel D: sequential GRU via MFMA (r12's 52.5 µs champion) ----------------
// 16 blocks = (dir, b), b = wgid&7 (XCD-local). 512 threads = 8 waves.
__global__ __launch_bounds__(512, 1) void gru_seq(const float* __restrict__ gi,
                                                  const float* __restrict__ gwh_f,
                                                  const float* __restrict__ gbh_f,
                                                  const float* __restrict__ gwh_b,
                                                  const float* __restrict__ gbh_b,
                                                  float* __restrict__ hcat) {
  __shared__ short hb[2][HH];  // 2 x 128 bf16
  int dir = blockIdx.x >> 3, b = blockIdx.x & 7;
  const float* Wh = dir ? gwh_b : gwh_f;
  const float* bh = dir ? gbh_b : gbh_f;
  int tid = threadIdx.x;
  int w = tid >> 6, l = tid & 63;
  int lhi = l >> 4, llo = l & 15;
  int o = 16 * w + llo;
  bool tl = (lhi == 0);

  for (int i = tid; i < 2 * HH / 2; i += 512) ((int*)hb)[i] = 0;

  short8v Bf[3][4];
#pragma unroll
  for (int g = 0; g < 3; g++) {
    const float* wr = Wh + (size_t)(g * HH + o) * EE;
#pragma unroll
    for (int kk = 0; kk < 4; kk++) {
      int k0 = kk * 32 + lhi * 8;
      short8v v;
#pragma unroll
      for (int i = 0; i < 8; i++) v[i] = f2bf(wr[k0 + i]);
      Bf[g][kk] = v;
    }
  }
  float bhr = bh[o], bhz = bh[HH + o], bhn = bh[2 * HH + o];
  float hprev = 0.f;
  float hst[16];  // store buffer, compile-time indices only

  float4 g0, g1, g2, g3;
  const size_t dbase = ((size_t)(dir * BB + b) * TQQ) * 512 + (size_t)o * 4;

  auto gi_load = [&](int step, float4& dst) {
    int tt = dir ? (TQQ - 1 - step) : step;
    dst = *(const float4*)(gi + dbase + (size_t)tt * 512);
  };
  __syncthreads();
  gi_load(0, g0); gi_load(1, g1);

  auto body = [&](int step, float4& gc, float4& gn, float& hs) {
    int cur = step & 1;
    const char* hrow = (const char*)&hb[cur][0];
    int ao = lhi * 16;
    short8v A0 = *(const short8v*)(hrow + 0 * 64 + ao);
    short8v A1 = *(const short8v*)(hrow + 1 * 64 + ao);
    short8v A2 = *(const short8v*)(hrow + 2 * 64 + ao);
    short8v A3 = *(const short8v*)(hrow + 3 * 64 + ao);
    { int ls = step + 2; gi_load(ls > TQQ - 1 ? TQQ - 1 : ls, gn); }
    f32x4 z4 = {0.f, 0.f, 0.f, 0.f};
    f32x4 aR = z4, aZ = z4, aN = z4;
    aR = MFMA16(A0, Bf[0][0], aR); aZ = MFMA16(A0, Bf[1][0], aZ); aN = MFMA16(A0, Bf[2][0], aN);
    aR = MFMA16(A1, Bf[0][1], aR); aZ = MFMA16(A1, Bf[1][1], aZ); aN = MFMA16(A1, Bf[2][1], aN);
    aR = MFMA16(A2, Bf[0][2], aR); aZ = MFMA16(A2, Bf[1][2], aZ); aN = MFMA16(A2, Bf[2][2], aN);
    aR = MFMA16(A3, Bf[0][3], aR); aZ = MFMA16(A3, Bf[1][3], aZ); aN = MFMA16(A3, Bf[2][3], aN);
    if (tl) {
      float rp = gc.x + bhr + aR[0];
      float zp = gc.y + bhz + aZ[0];
      float hn = aN[0] + bhn;
      float r = RCP(1.f + __expf(-rp));
      float z = RCP(1.f + __expf(-zp));
      float a = gc.z + r * hn;
      float e = __expf(2.f * a);
      float n = 1.f - 2.f * RCP(1.f + e);  // tanh(a), saturation-safe
      float hnew = n + z * (hprev - n);
      hprev = hnew;
      hs = hnew;
      hb[cur ^ 1][o] = f2bf(hnew);
    }
    asm volatile("s_waitcnt lgkmcnt(0)" ::: "memory");
    __builtin_amdgcn_s_barrier();
    __builtin_amdgcn_sched_barrier(0);
  };

  for (int so = 0; so < TQQ / 16; so++) {
    int s0i = so * 16;
    body(s0i + 0,  g0, g2, hst[0]);
    body(s0i + 1,  g1, g3, hst[1]);
    body(s0i + 2,  g2, g0, hst[2]);
    body(s0i + 3,  g3, g1, hst[3]);
    body(s0i + 4,  g0, g2, hst[4]);
    body(s0i + 5,  g1, g3, hst[5]);
    body(s0i + 6,  g2, g0, hst[6]);
    body(s0i + 7,  g3, g1, hst[7]);
    body(s0i + 8,  g0, g2, hst[8]);
    body(s0i + 9,  g1, g3, hst[9]);
    body(s0i + 10, g2, g0, hst[10]);
    body(s0i + 11, g3, g1, hst[11]);
    body(s0i + 12, g0, g2, hst[12]);
    body(s0i + 13, g1, g3, hst[13]);
    body(s0i + 14, g2, g0, hst[14]);
    body(s0i + 15, g3, g1, hst[15]);
    if (tl) {
#pragma unroll
      for (int si = 0; si < 16; si++) {
        int step = s0i + si;
        int t = dir ? (TQQ - 1 - step) : step;
        hcat[((size_t)b * TQQ + t) * (2 * HH) + dir * HH + o] = hst[si];
      }
    }
  }
}

// ---------------- Kernel E: final MLP, 8 rows/block ----------------
__global__ __launch_bounds__(512) void mlp_out(const float* __restrict__ hcat,
                                               const float* __restrict__ W1,
                                               const float* __restrict__ b1,
                                               const float* __restrict__ W2,
                                               const float* __restrict__ b2,
                                               float* __restrict__ out) {
  __shared__ float hrow[8][2 * HH];
  __shared__ float ybuf[8][52];
  int i = blockIdx.x;
  int b = i & 7, tg = i >> 3;
  int tid = threadIdx.x;
  size_t rowbase = (size_t)(b * TQQ + tg * 8) * (2 * HH);
  ((float4*)hrow)[tid] = *(const float4*)(hcat + rowbase + tid * 4);
  __syncthreads();
  int r = tid >> 6, o = tid & 63;
  if (o < NL) {
    const float4* w1 = (const float4*)(W1 + (size_t)o * (2 * HH));
    const float4* h4 = (const float4*)hrow[r];
    float acc = b1[o];
#pragma unroll 8
    for (int c = 0; c < 64; c++) acc += dot4(w1[c], h4[c]);
    ybuf[r][o] = fmaxf(acc, 0.f);
  }
  __syncthreads();
  if (o < OD) {
    const float* w2 = W2 + (size_t)o * NL;
    float acc = b2[o];
#pragma unroll 10
    for (int j = 0; j < NL; j++) acc += w2[j] * ybuf[r][j];
    out[((size_t)(b * TQQ + tg * 8) + r) * OD + o] = acc;
  }
}

extern "C" void kernel_launch(void* const* d_in, const int* in_sizes, int n_in,
                              void* d_out, int out_size, void* d_ws, size_t ws_size,
                              hipStream_t stream) {
  const float* x          = (const float*)d_in[0];
  const float* time_steps = (const float*)d_in[1];
  const float* query      = (const float*)d_in[2];
  const float* e1_wp = (const float*)d_in[3];
  const float* e1_bp = (const float*)d_in[4];
  const float* e1_wl = (const float*)d_in[5];
  const float* e1_bl = (const float*)d_in[6];
  const float* e2_wp = (const float*)d_in[7];
  const float* e2_bp = (const float*)d_in[8];
  const float* e2_wl = (const float*)d_in[9];
  const float* e2_bl = (const float*)d_in[10];
  const float* Wq = (const float*)d_in[11];
  const float* bq = (const float*)d_in[12];
  const float* Wk = (const float*)d_in[13];
  const float* bk = (const float*)d_in[14];
  const float* Wo = (const float*)d_in[15];
  const float* bo = (const float*)d_in[16];
  const float* gwi_f = (const float*)d_in[17];
  const float* gwh_f = (const float*)d_in[18];
  const float* gbi_f = (const float*)d_in[19];
  const float* gbh_f = (const float*)d_in[20];
  const float* gwi_b = (const float*)d_in[21];
  const float* gwh_b = (const float*)d_in[22];
  const float* gbi_b = (const float*)d_in[23];
  const float* gbh_b = (const float*)d_in[24];
  const float* W1 = (const float*)d_in[25];
  const float* b1 = (const float*)d_in[26];
  const float* W2 = (const float*)d_in[27];
  const float* b2 = (const float*)d_in[28];

  float* ws    = (float*)d_ws;
  float* kproj = ws;                        // 4096*128
  float* qproj = kproj + 4096 * 128;        // 128*128
  float* gi    = qproj + 128 * 128;         // float4 [16*128][128]
  float* hcat  = gi + 16 * 128 * 128 * 4;   // 8*128*256

  embed_project<<<528, 128, 0, stream>>>(time_steps, query,
                                         e1_wp, e1_bp, e1_wl, e1_bl,
                                         e2_wp, e2_bp, e2_wl, e2_bl,
                                         Wk, bk, Wq, bq, kproj, qproj);
  attention<<<256, 512, 0, stream>>>(x, kproj, qproj, Wo, bo,
                                     gwi_f, gbi_f, gwi_b, gbi_b, gi);
  gru_seq<<<16, 512, 0, stream>>>(gi, gwh_f, gbh_f, gwh_b, gbh_b, hcat);
  mlp_out<<<128, 512, 0, stream>>>(hcat, W1, b1, W2, b2, (float*)d_out);
}